// Round 2
// baseline (1483.171 us; speedup 1.0000x reference)
//
#include <hip/hip_runtime.h>
#include <hip/hip_fp16.h>
#include <math.h>

// BatchSpectralLoss: out = lambda_max(A^T A), A = 8192x4096 fp32 (k==1).
// SINGLE fused kernel (convert fp32->fp16 + 16-step Lanczos + Sturm solve)
// with a MANUAL grid barrier. Round-1 post-mortem: hipLaunchCooperativeKernel
// silently failed under the harness's graph capture (out stayed 0 => error ==
// ref exactly). Replacement: 256 blocks (1 per CU -> co-residency structural,
// no cooperative validation), single-use monotonic barrier counters in ws
// (zeroed by a captured hipMemsetAsync), AGENT-scope acq/rel atomics so the
// barrier also handles cross-XCD L2 visibility (guide §6 G16).
// Dispatch count 49 -> 2; ~600us of launch overhead removed.
//
// ws float layout: vb0/vb1/vb2 at 0/4096/8192, slots at 12288
//   (alpha[j]=slots[j], norm2[j]=slots[64+j]), barrier counters at 12416
//   (64 uints, memset to 0 each launch), partials at 262144 (256x4096).
// Ah (fp16 copy) at byte offset 16 MiB.

#define NROWS 8192
#define NCOLS 4096
#define T_STEPS 16
#define NBLK 256
#define RPC 8            // rows per chunk per block
#define NCHUNK 4         // NROWS / (NBLK * RPC)

__device__ __forceinline__ float slot_ld(const float* p) {
    return __hip_atomic_load(p, __ATOMIC_RELAXED, __HIP_MEMORY_SCOPE_AGENT);
}

// Grid barrier: one single-use counter per call site. All NBLK blocks add 1;
// everyone spins until the count is full. RMW release-sequence => every
// block's prior writes are visible after the acquiring load sees NBLK.
__device__ __forceinline__ void gbar(unsigned* cnt) {
    __syncthreads();
    if (threadIdx.x == 0) {
        __threadfence();
        __hip_atomic_fetch_add(cnt, 1u, __ATOMIC_ACQ_REL, __HIP_MEMORY_SCOPE_AGENT);
        while (__hip_atomic_load(cnt, __ATOMIC_ACQUIRE, __HIP_MEMORY_SCOPE_AGENT) < NBLK) {
            __builtin_amdgcn_s_sleep(2);
        }
        __threadfence();
    }
    __syncthreads();
}

__device__ __forceinline__ void up8(const float4& p, float* f) {
    const __half2* h = (const __half2*)&p;
    float2 t0 = __half22float2(h[0]);
    float2 t1 = __half22float2(h[1]);
    float2 t2 = __half22float2(h[2]);
    float2 t3 = __half22float2(h[3]);
    f[0] = t0.x; f[1] = t0.y; f[2] = t1.x; f[3] = t1.y;
    f[4] = t2.x; f[5] = t2.y; f[6] = t3.x; f[7] = t3.y;
}

__global__ __launch_bounds__(256, 2) void lanczos_fused(const float* __restrict__ A,
                                                        __half* __restrict__ Ah,
                                                        float* __restrict__ ws,
                                                        float* __restrict__ out) {
    __shared__ __align__(16) float smem[192];
    float* slots = ws + 12288;
    unsigned* bars = (unsigned*)(ws + 12416);
    float* partials = ws + 262144;
    const int tid = threadIdx.x;
    const int bid = blockIdx.x;
    const int gtid = bid * 256 + tid;
    int bix = 0;

    // ---------------- Phase A: fp32->fp16 convert + state init ----------------
    {
        const float4* A4 = (const float4*)A;
        float2* O2 = (float2*)Ah;
#pragma unroll 4
        for (int i = gtid; i < (NROWS * NCOLS / 4); i += NBLK * 256) {
            float4 f = A4[i];
            union { float2 f2; __half2 h2[2]; } u;
            u.h2[0] = __halves2half2(__float2half_rn(f.x), __float2half_rn(f.y));
            u.h2[1] = __halves2half2(__float2half_rn(f.z), __float2half_rn(f.w));
            O2[i] = u.f2;
        }
        if (gtid < NCOLS) {
            unsigned h = (unsigned)gtid * 2654435761u;
            h ^= h >> 16; h *= 2246822519u; h ^= h >> 13;
            ws[4096 + gtid] = (h & 1u) ? 0.015625f : -0.015625f;  // vb[1] = r1 (j=1 rc)
            ws[gtid] = 0.f;                                        // vb[0] = r0 (j=1 rp)
            if (gtid < 128) slots[gtid] = (gtid == 64 || gtid == 65) ? 1.f : 0.f;
        }
    }
    gbar(&bars[bix++]);

    for (int j = 1; j <= T_STEPS; ++j) {
        const float* rc = ws + 4096 * (j % 3);
        const float* rp = ws + 4096 * ((j + 2) % 3);
        float* wt = ws + 4096 * ((j + 1) % 3);

        // ---------------- bmv phase: partials = per-block A^T(Av), alpha ----
        {
            int lane = tid & 63;
            float inv = rsqrtf(fmaxf(slot_ld(&slots[64 + j]), 1e-30f));
            int cA = tid * 8, cB = 2048 + tid * 8;
            float vA[8], vB[8];
            {
                const float4* r4 = (const float4*)(rc + cA);
                float4 x = r4[0], y = r4[1];
                vA[0] = x.x * inv; vA[1] = x.y * inv; vA[2] = x.z * inv; vA[3] = x.w * inv;
                vA[4] = y.x * inv; vA[5] = y.y * inv; vA[6] = y.z * inv; vA[7] = y.w * inv;
                const float4* s4 = (const float4*)(rc + cB);
                float4 z = s4[0], w4 = s4[1];
                vB[0] = z.x * inv; vB[1] = z.y * inv; vB[2] = z.z * inv; vB[3] = z.w * inv;
                vB[4] = w4.x * inv; vB[5] = w4.y * inv; vB[6] = w4.z * inv; vB[7] = w4.w * inv;
            }
            float wacc[16];
#pragma unroll
            for (int i = 0; i < 16; ++i) wacc[i] = 0.f;

#pragma unroll 1
            for (int ch = 0; ch < NCHUNK; ++ch) {
                int row0 = ch * (NBLK * RPC) + bid * RPC;
                const __half* base = Ah + (size_t)row0 * NCOLS;
                float4 alo[RPC], ahi[RPC];
#pragma unroll
                for (int r = 0; r < RPC; ++r) {
                    alo[r] = *(const float4*)(base + (size_t)r * NCOLS + cA);
                    ahi[r] = *(const float4*)(base + (size_t)r * NCOLS + cB);
                }
                __syncthreads();                       // prior chunk's smem readers done
                if (tid < RPC) smem[tid] = 0.f;
                __syncthreads();
#pragma unroll
                for (int r = 0; r < RPC; ++r) {
                    float f[8];
                    up8(alo[r], f);
                    float sp = f[0] * vA[0] + f[1] * vA[1] + f[2] * vA[2] + f[3] * vA[3]
                             + f[4] * vA[4] + f[5] * vA[5] + f[6] * vA[6] + f[7] * vA[7];
                    up8(ahi[r], f);
                    sp += f[0] * vB[0] + f[1] * vB[1] + f[2] * vB[2] + f[3] * vB[3]
                        + f[4] * vB[4] + f[5] * vB[5] + f[6] * vB[6] + f[7] * vB[7];
#pragma unroll
                    for (int off = 32; off > 0; off >>= 1) sp += __shfl_xor(sp, off);
                    if (lane == 0) atomicAdd(&smem[r], sp);
                }
                __syncthreads();
                if (tid == 0) {                        // alpha += sum_r s_r^2
                    float aa = 0.f;
#pragma unroll
                    for (int r = 0; r < RPC; ++r) aa += smem[r] * smem[r];
                    atomicAdd(&slots[j], aa);
                }
#pragma unroll
                for (int r = 0; r < RPC; ++r) {        // w += s_r * A_r (per-thread)
                    float s = smem[r];
                    float f[8];
                    up8(alo[r], f);
                    wacc[0] += s * f[0]; wacc[1] += s * f[1]; wacc[2] += s * f[2]; wacc[3] += s * f[3];
                    wacc[4] += s * f[4]; wacc[5] += s * f[5]; wacc[6] += s * f[6]; wacc[7] += s * f[7];
                    up8(ahi[r], f);
                    wacc[8] += s * f[0]; wacc[9] += s * f[1]; wacc[10] += s * f[2]; wacc[11] += s * f[3];
                    wacc[12] += s * f[4]; wacc[13] += s * f[5]; wacc[14] += s * f[6]; wacc[15] += s * f[7];
                }
            }
            float* pb = partials + (size_t)bid * NCOLS;
            float4* pa = (float4*)(pb + cA);
            pa[0] = make_float4(wacc[0], wacc[1], wacc[2], wacc[3]);
            pa[1] = make_float4(wacc[4], wacc[5], wacc[6], wacc[7]);
            float4* pc = (float4*)(pb + cB);
            pc[0] = make_float4(wacc[8], wacc[9], wacc[10], wacc[11]);
            pc[1] = make_float4(wacc[12], wacc[13], wacc[14], wacc[15]);
        }
        gbar(&bars[bix++]);

        if (j < T_STEPS) {
            // ------------- fused reduce: 256 partials -> w, recurrence, beta --
            // Block b owns cols [16b, 16b+16). Thread: q=tid&3 (col-quad),
            // p0=tid>>2 (partial row); sums rows {p0, p0+64, p0+128, p0+192}.
            {
                int q = tid & 3, p0 = tid >> 2;
                float4 s = make_float4(0.f, 0.f, 0.f, 0.f);
#pragma unroll
                for (int i = 0; i < 4; ++i) {
                    const float4 v = *(const float4*)(partials
                        + (size_t)(p0 + i * 64) * NCOLS + bid * 16 + q * 4);
                    s.x += v.x; s.y += v.y; s.z += v.z; s.w += v.w;
                }
#pragma unroll
                for (int off = 4; off <= 32; off <<= 1) {   // reduce over p0 within wave
                    s.x += __shfl_xor(s.x, off);
                    s.y += __shfl_xor(s.y, off);
                    s.z += __shfl_xor(s.z, off);
                    s.w += __shfl_xor(s.w, off);
                }
                int lane = tid & 63, wv = tid >> 6;
                if (lane < 4) *(float4*)&smem[wv * 16 + lane * 4] = s;
                __syncthreads();
                if (tid < 16) {
                    int col = bid * 16 + tid;
                    float wsum = smem[tid] + smem[16 + tid] + smem[32 + tid] + smem[48 + tid];
                    float a = slot_ld(&slots[j]);
                    float n2j = fmaxf(slot_ld(&slots[64 + j]), 1e-30f);
                    float n2m = fmaxf(slot_ld(&slots[64 + j - 1]), 1e-30f);
                    float invj = rsqrtf(n2j);
                    float cb = sqrtf(n2j / n2m);               // beta_{j-1}/||r_{j-1}||
                    float rn = wsum - a * invj * rc[col] - cb * rp[col];
                    wt[col] = rn;
                    float p = rn * rn;
                    p += __shfl_xor(p, 1);
                    p += __shfl_xor(p, 2);
                    p += __shfl_xor(p, 4);
                    p += __shfl_xor(p, 8);
                    if (tid == 0) atomicAdd(&slots[64 + j + 1], p);
                }
            }
            gbar(&bars[bix++]);
        }
    }

    // ---------------- solve: largest eig of tridiag via Sturm (block 0) -------
    if (bid == 0) {
        const int t = T_STEPS;
        float* d_s = smem;
        float* e2_s = smem + 64;
        if (tid < 64) {
            d_s[tid] = (tid < t) ? slot_ld(&slots[1 + tid]) : 0.f;
            e2_s[tid] = (tid < t - 1) ? slot_ld(&slots[64 + tid + 2]) : 0.f;
        }
        __syncthreads();
        if (tid < 64) {
            int lane = tid;
            float e_here = sqrtf(e2_s[lane]);
            float e_prev = (lane > 0) ? sqrtf(e2_s[lane - 1]) : 0.f;
            float d = d_s[lane];
            float gersh = (lane < t) ? d + e_here + e_prev : 0.f;
            float dmax = (lane < t) ? d : 0.f;
#pragma unroll
            for (int off = 32; off > 0; off >>= 1) {
                gersh = fmaxf(gersh, __shfl_xor(gersh, off));
                dmax = fmaxf(dmax, __shfl_xor(dmax, off));
            }
            float lo = dmax, hi = gersh + 1e-3f;
            for (int round = 0; round < 3; ++round) {
                float stepw = (hi - lo) * (1.f / 64.f);
                float x = lo + stepw * (lane + 1);
                double qv = 1.0;
                int cnt = 0;
                for (int i = 0; i < t; ++i) {
                    double qi = (double)d_s[i] - (double)x - ((i > 0) ? (double)e2_s[i - 1] / qv : 0.0);
                    if (fabs(qi) < 1e-300) qi = -1e-300;
                    cnt += (qi < 0.0);
                    qv = qi;
                }
                unsigned long long m = __ballot(cnt < t);
                if (m) {
                    int h = 63 - __clzll(m);
                    lo = lo + stepw * (h + 1);
                    hi = lo + stepw;
                } else {
                    hi = lo + stepw;
                }
            }
            if (tid == 0) out[0] = 0.5f * (lo + hi);
        }
    }
}

extern "C" void kernel_launch(void* const* d_in, const int* in_sizes, int n_in,
                              void* d_out, int out_size, void* d_ws, size_t ws_size,
                              hipStream_t stream) {
    const float* A = (const float*)d_in[0];
    float* out = (float*)d_out;
    float* ws = (float*)d_ws;
    __half* Ah = (__half*)((char*)d_ws + (size_t)16 * 1024 * 1024);

    // Zero the 64 single-use barrier counters (ws floats 12416..12480).
    hipMemsetAsync((char*)d_ws + (size_t)12416 * 4, 0, 64 * sizeof(unsigned), stream);

    lanczos_fused<<<NBLK, 256, 0, stream>>>(A, Ah, ws, out);
}

// Round 5
// 1339.589 us; speedup vs baseline: 1.1072x; 1.1072x over previous
//
#include <hip/hip_runtime.h>
#include <hip/hip_fp16.h>
#include <math.h>

// BatchSpectralLoss: out = lambda_max(A^T A), A = 8192x4096 fp32 (k==1).
// SINGLE fused kernel (convert fp32->fp16 + 16-step Lanczos + Sturm solve)
// with a manual grid barrier.
// R2: acquire-spin barrier ran correctly but each poll's buffer_inv trashed
//     L1/L2 (VALUBusy 3.9%, 1366us).
// R3/R4: relaxed-spin barrier -> container death x2. Root cause: relaxed
//     agent atomic LOADS are served from the local per-XCD L2 (no cross-XCD
//     coherence) -> spinners never see remote RMWs -> hang; R4's spin bound
//     (~2.3s/barrier x33) still looked like a hang.
// THIS round: coherence-point loads WITHOUT cache ops — inline-asm
//     global_load ... sc0 sc1 (reads the IC, no invalidation; AITER split-k
//     pattern). Arrivals = atomic RMW (always executes at IC). Writers do ONE
//     release fence per barrier (buffer_wbl2 = writeback, keeps clean L2
//     copies). NO acquire fence: all cross-block data (partials, vb, slots,
//     counters) is bypass-read, so Ah STAYS L2-resident all 16 steps.
//     Spin bounded ~170ms + sticky err word (checked in-spin) -> worst case
//     ~0.3s stall, solver emits -1e7-gen => diagnosable, container-safe.
//
// ws float layout: vb0/vb1/vb2 at 0/4096/8192, slots at 12288
//   (alpha[j]=slots[j], norm2[j]=slots[64+j]), barrier at 12416
//   (8 arrive counters 64B-spaced, release gen at uint +192, err at +200;
//   1024B memset each launch), partials at 262144 (512x4096, ends 9 MiB).
// Ah fp16 at byte 16 MiB.

#define NROWS 8192
#define NCOLS 4096
#define T_STEPS 16
#define NBLK 512
#define RPC 8            // rows per chunk per block
#define NCHUNK 2         // NROWS / (NBLK * RPC)
#define SPIN_LIMIT 200000L

// ---- coherence-point (Infinity Cache) accessors: bypass L1+L2, no cache ops
__device__ __forceinline__ unsigned ic_ld_u32(const unsigned* p) {
    unsigned v;
    asm volatile("global_load_dword %0, %1, off sc0 sc1\n\ts_waitcnt vmcnt(0)"
                 : "=v"(v) : "v"(p) : "memory");
    return v;
}
__device__ __forceinline__ float ic_ld_f32(const float* p) {
    float v;
    asm volatile("global_load_dword %0, %1, off sc0 sc1\n\ts_waitcnt vmcnt(0)"
                 : "=v"(v) : "v"(p) : "memory");
    return v;
}
__device__ __forceinline__ void ic_st_u32(unsigned* p, unsigned v) {
    asm volatile("global_store_dword %0, %1, off sc0 sc1"
                 :: "v"(p), "v"(v) : "memory");
}
__device__ __forceinline__ unsigned ic_sum4_u32(const unsigned* p0, const unsigned* p1,
                                                const unsigned* p2, const unsigned* p3) {
    unsigned a, b, c, d;
    asm volatile(
        "global_load_dword %0, %4, off sc0 sc1\n\t"
        "global_load_dword %1, %5, off sc0 sc1\n\t"
        "global_load_dword %2, %6, off sc0 sc1\n\t"
        "global_load_dword %3, %7, off sc0 sc1\n\t"
        "s_waitcnt vmcnt(0)"
        : "=&v"(a), "=&v"(b), "=&v"(c), "=&v"(d)
        : "v"(p0), "v"(p1), "v"(p2), "v"(p3) : "memory");
    return a + b + c + d;
}
__device__ __forceinline__ void ic_ld4_f32x4(const float* p0, const float* p1,
                                             const float* p2, const float* p3,
                                             float4& a, float4& b, float4& c, float4& d) {
    asm volatile(
        "global_load_dwordx4 %0, %4, off sc0 sc1\n\t"
        "global_load_dwordx4 %1, %5, off sc0 sc1\n\t"
        "global_load_dwordx4 %2, %6, off sc0 sc1\n\t"
        "global_load_dwordx4 %3, %7, off sc0 sc1\n\t"
        "s_waitcnt vmcnt(0)"
        : "=&v"(a), "=&v"(b), "=&v"(c), "=&v"(d)
        : "v"(p0), "v"(p1), "v"(p2), "v"(p3) : "memory");
}

__device__ __forceinline__ void up8(const float4& p, float* f) {
    const __half2* h = (const __half2*)&p;
    float2 t0 = __half22float2(h[0]);
    float2 t1 = __half22float2(h[1]);
    float2 t2 = __half22float2(h[2]);
    float2 t3 = __half22float2(h[3]);
    f[0] = t0.x; f[1] = t0.y; f[2] = t1.x; f[3] = t1.y;
    f[4] = t2.x; f[5] = t2.y; f[6] = t3.x; f[7] = t3.y;
}

// Grid barrier, generation 'gen' (1-based monotonic; state memset per launch).
// Writer side: release fence (wbl2 writeback, keeps clean lines) + arrive RMW.
// Reader side: bypass-load polls only (no cache maintenance). Bounded + sticky
// error word so failure is a wrong answer, never a hang.
__device__ __forceinline__ void gbar(unsigned* arrive, unsigned* release,
                                     unsigned* errw, unsigned gen, int bid) {
    __syncthreads();   // all waves' stores issued (waitcnt before s_barrier)
    if (threadIdx.x == 0) {
        __builtin_amdgcn_fence(__ATOMIC_RELEASE, "agent");   // wb dirty L2 -> IC
        asm volatile("s_waitcnt vmcnt(0)" ::: "memory");
        __hip_atomic_fetch_add(&arrive[(bid & 7) * 16], 1u,
                               __ATOMIC_RELAXED, __HIP_MEMORY_SCOPE_AGENT);
        if (ic_ld_u32(errw) == 0) {
            long iters = 0;
            if (bid == 0) {
                const unsigned target = gen * NBLK;
                for (;;) {
                    unsigned s = ic_sum4_u32(&arrive[0], &arrive[16], &arrive[32], &arrive[48])
                               + ic_sum4_u32(&arrive[64], &arrive[80], &arrive[96], &arrive[112]);
                    if (s >= target) break;
                    if (++iters > SPIN_LIMIT) { ic_st_u32(errw, gen); break; }
                    if ((iters & 255) == 0 && ic_ld_u32(errw)) break;
                    for (int k = 0; k < 8; ++k) __builtin_amdgcn_s_sleep(7);
                }
                ic_st_u32(release, gen);
            } else {
                while (ic_ld_u32(release) < gen) {
                    if (++iters > SPIN_LIMIT) { ic_st_u32(errw, gen); break; }
                    if ((iters & 255) == 0 && ic_ld_u32(errw)) break;
                    for (int k = 0; k < 8; ++k) __builtin_amdgcn_s_sleep(7);
                }
            }
        }
    }
    __syncthreads();
}

__global__ __launch_bounds__(256, 4) void lanczos_fused(const float* __restrict__ A,
                                                        __half* __restrict__ Ah,
                                                        float* __restrict__ ws,
                                                        float* __restrict__ out) {
    __shared__ __align__(16) float smem[192];
    float* slots = ws + 12288;
    unsigned* arrive = (unsigned*)(ws + 12416);    // 8 counters, 64B apart
    unsigned* release = (unsigned*)(ws + 12416) + 192;
    unsigned* errw = (unsigned*)(ws + 12416) + 200;
    float* partials = ws + 262144;
    const int tid = threadIdx.x;
    const int bid = blockIdx.x;
    const int gtid = bid * 256 + tid;
    unsigned gen = 0;

    // ---------------- Phase A: fp32->fp16 convert + state init ----------------
    {
        const float4* A4 = (const float4*)A;
        float2* O2 = (float2*)Ah;
#pragma unroll 4
        for (int i = gtid; i < (NROWS * NCOLS / 4); i += NBLK * 256) {
            float4 f = A4[i];
            union { float2 f2; __half2 h2[2]; } u;
            u.h2[0] = __halves2half2(__float2half_rn(f.x), __float2half_rn(f.y));
            u.h2[1] = __halves2half2(__float2half_rn(f.z), __float2half_rn(f.w));
            O2[i] = u.f2;
        }
        if (gtid < NCOLS) {
            unsigned h = (unsigned)gtid * 2654435761u;
            h ^= h >> 16; h *= 2246822519u; h ^= h >> 13;
            ws[4096 + gtid] = (h & 1u) ? 0.015625f : -0.015625f;  // vb[1] = r1 (j=1 rc)
            ws[gtid] = 0.f;                                        // vb[0] = r0 (j=1 rp)
            if (gtid < 128) slots[gtid] = (gtid == 64 || gtid == 65) ? 1.f : 0.f;
        }
    }
    gbar(arrive, release, errw, ++gen, bid);

    for (int j = 1; j <= T_STEPS; ++j) {
        const float* rc = ws + 4096 * (j % 3);
        const float* rp = ws + 4096 * ((j + 2) % 3);
        float* wt = ws + 4096 * ((j + 1) % 3);

        // ---------------- bmv phase: partials = per-block A^T(Av), alpha ----
        {
            int lane = tid & 63;
            float inv = rsqrtf(fmaxf(ic_ld_f32(&slots[64 + j]), 1e-30f));
            int cA = tid * 8, cB = 2048 + tid * 8;
            float vA[8], vB[8];
            {
                float4 x, y, z, w4;
                ic_ld4_f32x4(rc + cA, rc + cA + 4, rc + cB, rc + cB + 4, x, y, z, w4);
                vA[0] = x.x * inv; vA[1] = x.y * inv; vA[2] = x.z * inv; vA[3] = x.w * inv;
                vA[4] = y.x * inv; vA[5] = y.y * inv; vA[6] = y.z * inv; vA[7] = y.w * inv;
                vB[0] = z.x * inv; vB[1] = z.y * inv; vB[2] = z.z * inv; vB[3] = z.w * inv;
                vB[4] = w4.x * inv; vB[5] = w4.y * inv; vB[6] = w4.z * inv; vB[7] = w4.w * inv;
            }
            float wacc[16];
#pragma unroll
            for (int i = 0; i < 16; ++i) wacc[i] = 0.f;
            float aa_tot = 0.f;

#pragma unroll 1
            for (int ch = 0; ch < NCHUNK; ++ch) {
                int row0 = ch * (NBLK * RPC) + bid * RPC;
                const __half* base = Ah + (size_t)row0 * NCOLS;
                float4 alo[RPC], ahi[RPC];
#pragma unroll
                for (int r = 0; r < RPC; ++r) {
                    alo[r] = *(const float4*)(base + (size_t)r * NCOLS + cA);
                    ahi[r] = *(const float4*)(base + (size_t)r * NCOLS + cB);
                }
                __syncthreads();                       // prior chunk's smem readers done
                if (tid < RPC) smem[tid] = 0.f;
                __syncthreads();
#pragma unroll
                for (int r = 0; r < RPC; ++r) {
                    float f[8];
                    up8(alo[r], f);
                    float sp = f[0] * vA[0] + f[1] * vA[1] + f[2] * vA[2] + f[3] * vA[3]
                             + f[4] * vA[4] + f[5] * vA[5] + f[6] * vA[6] + f[7] * vA[7];
                    up8(ahi[r], f);
                    sp += f[0] * vB[0] + f[1] * vB[1] + f[2] * vB[2] + f[3] * vB[3]
                        + f[4] * vB[4] + f[5] * vB[5] + f[6] * vB[6] + f[7] * vB[7];
#pragma unroll
                    for (int off = 32; off > 0; off >>= 1) sp += __shfl_xor(sp, off);
                    if (lane == 0) atomicAdd(&smem[r], sp);
                }
                __syncthreads();
                if (tid == 0) {                        // alpha partial (atomic hoisted)
#pragma unroll
                    for (int r = 0; r < RPC; ++r) aa_tot += smem[r] * smem[r];
                }
#pragma unroll
                for (int r = 0; r < RPC; ++r) {        // w += s_r * A_r (per-thread)
                    float s = smem[r];
                    float f[8];
                    up8(alo[r], f);
                    wacc[0] += s * f[0]; wacc[1] += s * f[1]; wacc[2] += s * f[2]; wacc[3] += s * f[3];
                    wacc[4] += s * f[4]; wacc[5] += s * f[5]; wacc[6] += s * f[6]; wacc[7] += s * f[7];
                    up8(ahi[r], f);
                    wacc[8] += s * f[0]; wacc[9] += s * f[1]; wacc[10] += s * f[2]; wacc[11] += s * f[3];
                    wacc[12] += s * f[4]; wacc[13] += s * f[5]; wacc[14] += s * f[6]; wacc[15] += s * f[7];
                }
            }
            if (tid == 0) atomicAdd(&slots[j], aa_tot);
            float* pb = partials + (size_t)bid * NCOLS;
            float4* pa = (float4*)(pb + cA);
            pa[0] = make_float4(wacc[0], wacc[1], wacc[2], wacc[3]);
            pa[1] = make_float4(wacc[4], wacc[5], wacc[6], wacc[7]);
            float4* pc = (float4*)(pb + cB);
            pc[0] = make_float4(wacc[8], wacc[9], wacc[10], wacc[11]);
            pc[1] = make_float4(wacc[12], wacc[13], wacc[14], wacc[15]);
        }
        gbar(arrive, release, errw, ++gen, bid);

        if (j < T_STEPS) {
            // ------------- fused reduce: 512 partials -> w, recurrence, beta --
            // Block b owns cols [8b, 8b+8). Thread: q=tid&1 (col-quad),
            // p0=tid>>1; sums partial rows {p0, p0+128, p0+256, p0+384}.
            {
                int q = tid & 1, p0 = tid >> 1;
                const float* pb0 = partials + (size_t)p0 * NCOLS + bid * 8 + q * 4;
                float4 v0, v1, v2, v3;
                ic_ld4_f32x4(pb0, pb0 + (size_t)128 * NCOLS,
                             pb0 + (size_t)256 * NCOLS, pb0 + (size_t)384 * NCOLS,
                             v0, v1, v2, v3);
                float4 s;
                s.x = v0.x + v1.x + v2.x + v3.x;
                s.y = v0.y + v1.y + v2.y + v3.y;
                s.z = v0.z + v1.z + v2.z + v3.z;
                s.w = v0.w + v1.w + v2.w + v3.w;
#pragma unroll
                for (int off = 2; off <= 32; off <<= 1) {   // reduce over p0 in wave
                    s.x += __shfl_xor(s.x, off);
                    s.y += __shfl_xor(s.y, off);
                    s.z += __shfl_xor(s.z, off);
                    s.w += __shfl_xor(s.w, off);
                }
                int lane = tid & 63, wv = tid >> 6;
                if (lane < 2) *(float4*)&smem[wv * 8 + lane * 4] = s;
                __syncthreads();
                if (tid < 8) {
                    int col = bid * 8 + tid;
                    float wsum = smem[tid] + smem[8 + tid] + smem[16 + tid] + smem[24 + tid];
                    float a = ic_ld_f32(&slots[j]);
                    float n2j = fmaxf(ic_ld_f32(&slots[64 + j]), 1e-30f);
                    float n2m = fmaxf(ic_ld_f32(&slots[64 + j - 1]), 1e-30f);
                    float invj = rsqrtf(n2j);
                    float cb = sqrtf(n2j / n2m);               // beta_{j-1}/||r_{j-1}||
                    float rn = wsum - a * invj * ic_ld_f32(&rc[col]) - cb * ic_ld_f32(&rp[col]);
                    wt[col] = rn;
                    float p = rn * rn;
                    p += __shfl_xor(p, 1);
                    p += __shfl_xor(p, 2);
                    p += __shfl_xor(p, 4);
                    if (tid == 0) atomicAdd(&slots[64 + j + 1], p);
                }
            }
            gbar(arrive, release, errw, ++gen, bid);
        }
    }

    // ---------------- solve: largest eig of tridiag via Sturm (block 0) -------
    if (bid == 0) {
        const int t = T_STEPS;
        float* d_s = smem;
        float* e2_s = smem + 64;
        if (tid < 64) {
            d_s[tid] = (tid < t) ? ic_ld_f32(&slots[1 + tid]) : 0.f;
            e2_s[tid] = (tid < t - 1) ? ic_ld_f32(&slots[64 + tid + 2]) : 0.f;
        }
        __syncthreads();
        if (tid < 64) {
            int lane = tid;
            float e_here = sqrtf(e2_s[lane]);
            float e_prev = (lane > 0) ? sqrtf(e2_s[lane - 1]) : 0.f;
            float d = d_s[lane];
            float gersh = (lane < t) ? d + e_here + e_prev : 0.f;
            float dmax = (lane < t) ? d : 0.f;
#pragma unroll
            for (int off = 32; off > 0; off >>= 1) {
                gersh = fmaxf(gersh, __shfl_xor(gersh, off));
                dmax = fmaxf(dmax, __shfl_xor(dmax, off));
            }
            float lo = dmax, hi = gersh + 1e-3f;
            for (int round = 0; round < 3; ++round) {
                float stepw = (hi - lo) * (1.f / 64.f);
                float x = lo + stepw * (lane + 1);
                double qv = 1.0;
                int cnt = 0;
                for (int i = 0; i < t; ++i) {
                    double qi = (double)d_s[i] - (double)x - ((i > 0) ? (double)e2_s[i - 1] / qv : 0.0);
                    if (fabs(qi) < 1e-300) qi = -1e-300;
                    cnt += (qi < 0.0);
                    qv = qi;
                }
                unsigned long long m = __ballot(cnt < t);
                if (m) {
                    int h = 63 - __clzll(m);
                    lo = lo + stepw * (h + 1);
                    hi = lo + stepw;
                } else {
                    hi = lo + stepw;
                }
            }
            if (tid == 0) {
                unsigned e = ic_ld_u32(errw);
                out[0] = e ? (-1.0e7f - (float)e) : 0.5f * (lo + hi);
            }
        }
    }
}

extern "C" void kernel_launch(void* const* d_in, const int* in_sizes, int n_in,
                              void* d_out, int out_size, void* d_ws, size_t ws_size,
                              hipStream_t stream) {
    const float* A = (const float*)d_in[0];
    float* out = (float*)d_out;
    float* ws = (float*)d_ws;
    __half* Ah = (__half*)((char*)d_ws + (size_t)16 * 1024 * 1024);

    // Zero barrier state: arrive counters + release gen + err (1024 B).
    hipMemsetAsync((char*)d_ws + (size_t)12416 * 4, 0, 1024, stream);

    lanczos_fused<<<NBLK, 256, 0, stream>>>(A, Ah, ws, out);
}

// Round 7
// 1040.567 us; speedup vs baseline: 1.4253x; 1.2874x over previous
//
#include <hip/hip_runtime.h>
#include <hip/hip_fp16.h>
#include <math.h>

// BatchSpectralLoss: out = lambda_max(A^T A), A = 8192x4096 fp32 (k==1).
// SINGLE fused kernel (convert fp32->fp16 + 16-step Lanczos + Sturm solve)
// with a manual fence-free grid barrier.
// R2: acquire-spin barrier: per-poll buffer_inv trashed caches. 1366us.
// R3/R4: relaxed-spin: stale per-XCD L2 -> spinners hang -> container death.
// R5: bypass-load (sc0 sc1) spin: correct, 1249us — but VALUBusy still 4.6%.
//     => spin flavor was never the main cost.
// R5 post-mortem: the remaining ~35us/barrier x33 is the per-block AGENT
//     RELEASE FENCE: fence(RELEASE,"agent") = s_waitcnt + buffer_wbl2, a full
//     L2 tag-scan writeback (32K lines ~ 13.6us/scan; 64 blocks/XCD issue it
//     per barrier). Present in BOTH R2 and R5 -> explains both ~1.3ms times.
// R6: fence-free design failed to COMPILE: asm 'v' input constraint can't
//     take HIP float4 (struct) by value ("indirect register inputs").
// THIS round: same design, asm vector operands passed as clang ext_vector
//     types (lower natively to VGPR quads). Zero fences: every cross-block
//     WRITE is write-through sc0 sc1 (Ah convert, partials, wt, vb/slots
//     init) so L2 never holds dirty shared lines; every cross-block READ is
//     a bypass load. Barrier = syncthreads + vmcnt(0) + arrive RMW + bypass
//     spin. L2 never invalidated -> Ah stays L2-resident all 16 steps.
//     Bounded spin + sticky err sentinel kept (failure => out=-1e7-gen).
//
// ws float layout: vb0/vb1/vb2 at 0/4096/8192, slots at 12288
//   (alpha[j]=slots[j], norm2[j]=slots[64+j]), barrier at 12416
//   (8 arrive counters 64B-spaced, release gen at uint +192, err at +200;
//   1024B memset each launch), partials at 262144 (512x4096, ends 9 MiB).
// Ah fp16 at byte 16 MiB.

#define NROWS 8192
#define NCOLS 4096
#define T_STEPS 16
#define NBLK 512
#define RPC 8            // rows per chunk per block
#define NCHUNK 2         // NROWS / (NBLK * RPC)
#define SPIN_LIMIT 200000L

typedef float f32x4_t __attribute__((ext_vector_type(4)));
typedef float f32x2_t __attribute__((ext_vector_type(2)));

// ---- coherence-point (Infinity Cache) accessors: bypass L1+L2, no cache ops
__device__ __forceinline__ unsigned ic_ld_u32(const unsigned* p) {
    unsigned v;
    asm volatile("global_load_dword %0, %1, off sc0 sc1\n\ts_waitcnt vmcnt(0)"
                 : "=v"(v) : "v"(p) : "memory");
    return v;
}
__device__ __forceinline__ float ic_ld_f32(const float* p) {
    float v;
    asm volatile("global_load_dword %0, %1, off sc0 sc1\n\ts_waitcnt vmcnt(0)"
                 : "=v"(v) : "v"(p) : "memory");
    return v;
}
__device__ __forceinline__ void ic_st_u32(unsigned* p, unsigned v) {
    asm volatile("global_store_dword %0, %1, off sc0 sc1"
                 :: "v"(p), "v"(v) : "memory");
}
__device__ __forceinline__ void ic_st_f32(float* p, float v) {
    asm volatile("global_store_dword %0, %1, off sc0 sc1"
                 :: "v"(p), "v"(v) : "memory");
}
__device__ __forceinline__ void ic_st2_f32(float2* p, float2 v) {
    f32x2_t x; x.x = v.x; x.y = v.y;
    asm volatile("global_store_dwordx2 %0, %1, off sc0 sc1"
                 :: "v"(p), "v"(x) : "memory");
}
__device__ __forceinline__ void ic_st4_f32(float* p, float4 v) {
    f32x4_t x; x.x = v.x; x.y = v.y; x.z = v.z; x.w = v.w;
    asm volatile("global_store_dwordx4 %0, %1, off sc0 sc1"
                 :: "v"(p), "v"(x) : "memory");
}
__device__ __forceinline__ unsigned ic_sum4_u32(const unsigned* p0, const unsigned* p1,
                                                const unsigned* p2, const unsigned* p3) {
    unsigned a, b, c, d;
    asm volatile(
        "global_load_dword %0, %4, off sc0 sc1\n\t"
        "global_load_dword %1, %5, off sc0 sc1\n\t"
        "global_load_dword %2, %6, off sc0 sc1\n\t"
        "global_load_dword %3, %7, off sc0 sc1\n\t"
        "s_waitcnt vmcnt(0)"
        : "=&v"(a), "=&v"(b), "=&v"(c), "=&v"(d)
        : "v"(p0), "v"(p1), "v"(p2), "v"(p3) : "memory");
    return a + b + c + d;
}
__device__ __forceinline__ void ic_ld4_f32x4(const float* p0, const float* p1,
                                             const float* p2, const float* p3,
                                             float4& ao, float4& bo, float4& co, float4& do_) {
    f32x4_t a, b, c, d;
    asm volatile(
        "global_load_dwordx4 %0, %4, off sc0 sc1\n\t"
        "global_load_dwordx4 %1, %5, off sc0 sc1\n\t"
        "global_load_dwordx4 %2, %6, off sc0 sc1\n\t"
        "global_load_dwordx4 %3, %7, off sc0 sc1\n\t"
        "s_waitcnt vmcnt(0)"
        : "=&v"(a), "=&v"(b), "=&v"(c), "=&v"(d)
        : "v"(p0), "v"(p1), "v"(p2), "v"(p3) : "memory");
    ao = make_float4(a.x, a.y, a.z, a.w);
    bo = make_float4(b.x, b.y, b.z, b.w);
    co = make_float4(c.x, c.y, c.z, c.w);
    do_ = make_float4(d.x, d.y, d.z, d.w);
}

__device__ __forceinline__ void up8(const float4& p, float* f) {
    const __half2* h = (const __half2*)&p;
    float2 t0 = __half22float2(h[0]);
    float2 t1 = __half22float2(h[1]);
    float2 t2 = __half22float2(h[2]);
    float2 t3 = __half22float2(h[3]);
    f[0] = t0.x; f[1] = t0.y; f[2] = t1.x; f[3] = t1.y;
    f[4] = t2.x; f[5] = t2.y; f[6] = t3.x; f[7] = t3.y;
}

// Fence-free grid barrier, generation 'gen' (1-based monotonic; state memset
// per launch). All cross-block data was WRITTEN THROUGH to the IC, so the only
// ordering needed is vmcnt(0) (stores acknowledged) before the arrive RMW.
// Readers poll with bypass loads. No cache maintenance instructions at all.
__device__ __forceinline__ void gbar(unsigned* arrive, unsigned* release,
                                     unsigned* errw, unsigned gen, int bid) {
    __syncthreads();   // all waves' stores issued
    if (threadIdx.x == 0) {
        asm volatile("s_waitcnt vmcnt(0)" ::: "memory");  // write-throughs at IC
        __hip_atomic_fetch_add(&arrive[(bid & 7) * 16], 1u,
                               __ATOMIC_RELAXED, __HIP_MEMORY_SCOPE_AGENT);
        if (ic_ld_u32(errw) == 0) {
            long iters = 0;
            if (bid == 0) {
                const unsigned target = gen * NBLK;
                for (;;) {
                    unsigned s = ic_sum4_u32(&arrive[0], &arrive[16], &arrive[32], &arrive[48])
                               + ic_sum4_u32(&arrive[64], &arrive[80], &arrive[96], &arrive[112]);
                    if (s >= target) break;
                    if (++iters > SPIN_LIMIT) { ic_st_u32(errw, gen); break; }
                    if ((iters & 255) == 0 && ic_ld_u32(errw)) break;
                    __builtin_amdgcn_s_sleep(2);
                }
                ic_st_u32(release, gen);
            } else {
                while (ic_ld_u32(release) < gen) {
                    if (++iters > SPIN_LIMIT) { ic_st_u32(errw, gen); break; }
                    if ((iters & 255) == 0 && ic_ld_u32(errw)) break;
                    __builtin_amdgcn_s_sleep(2);
                }
            }
        }
    }
    __syncthreads();
}

__global__ __launch_bounds__(256, 4) void lanczos_fused(const float* __restrict__ A,
                                                        __half* __restrict__ Ah,
                                                        float* __restrict__ ws,
                                                        float* __restrict__ out) {
    __shared__ __align__(16) float smem[192];
    float* slots = ws + 12288;
    unsigned* arrive = (unsigned*)(ws + 12416);    // 8 counters, 64B apart
    unsigned* release = (unsigned*)(ws + 12416) + 192;
    unsigned* errw = (unsigned*)(ws + 12416) + 200;
    float* partials = ws + 262144;
    const int tid = threadIdx.x;
    const int bid = blockIdx.x;
    const int gtid = bid * 256 + tid;
    unsigned gen = 0;

    // -------- Phase A: fp32->fp16 convert (write-through) + state init -------
    {
        const float4* A4 = (const float4*)A;
        float2* O2 = (float2*)Ah;
#pragma unroll 4
        for (int i = gtid; i < (NROWS * NCOLS / 4); i += NBLK * 256) {
            float4 f = A4[i];
            union { float2 f2; __half2 h2[2]; } u;
            u.h2[0] = __halves2half2(__float2half_rn(f.x), __float2half_rn(f.y));
            u.h2[1] = __halves2half2(__float2half_rn(f.z), __float2half_rn(f.w));
            ic_st2_f32(O2 + i, u.f2);
        }
        if (gtid < NCOLS) {
            unsigned h = (unsigned)gtid * 2654435761u;
            h ^= h >> 16; h *= 2246822519u; h ^= h >> 13;
            ic_st_f32(ws + 4096 + gtid, (h & 1u) ? 0.015625f : -0.015625f); // vb[1]
            ic_st_f32(ws + gtid, 0.f);                                      // vb[0]
            if (gtid < 128)
                ic_st_f32(slots + gtid, (gtid == 64 || gtid == 65) ? 1.f : 0.f);
        }
    }
    gbar(arrive, release, errw, ++gen, bid);

    for (int j = 1; j <= T_STEPS; ++j) {
        const float* rc = ws + 4096 * (j % 3);
        const float* rp = ws + 4096 * ((j + 2) % 3);
        float* wt = ws + 4096 * ((j + 1) % 3);

        // ---------------- bmv phase: partials = per-block A^T(Av), alpha ----
        {
            int lane = tid & 63;
            float inv = rsqrtf(fmaxf(ic_ld_f32(&slots[64 + j]), 1e-30f));
            int cA = tid * 8, cB = 2048 + tid * 8;
            float vA[8], vB[8];
            {
                float4 x, y, z, w4;
                ic_ld4_f32x4(rc + cA, rc + cA + 4, rc + cB, rc + cB + 4, x, y, z, w4);
                vA[0] = x.x * inv; vA[1] = x.y * inv; vA[2] = x.z * inv; vA[3] = x.w * inv;
                vA[4] = y.x * inv; vA[5] = y.y * inv; vA[6] = y.z * inv; vA[7] = y.w * inv;
                vB[0] = z.x * inv; vB[1] = z.y * inv; vB[2] = z.z * inv; vB[3] = z.w * inv;
                vB[4] = w4.x * inv; vB[5] = w4.y * inv; vB[6] = w4.z * inv; vB[7] = w4.w * inv;
            }
            float wacc[16];
#pragma unroll
            for (int i = 0; i < 16; ++i) wacc[i] = 0.f;
            float aa_tot = 0.f;

#pragma unroll 1
            for (int ch = 0; ch < NCHUNK; ++ch) {
                int row0 = ch * (NBLK * RPC) + bid * RPC;
                const __half* base = Ah + (size_t)row0 * NCOLS;
                float4 alo[RPC], ahi[RPC];
#pragma unroll
                for (int r = 0; r < RPC; ++r) {   // normal cached loads: Ah is
                    alo[r] = *(const float4*)(base + (size_t)r * NCOLS + cA);
                    ahi[r] = *(const float4*)(base + (size_t)r * NCOLS + cB);
                }                                  // immutable + write-through'd
                __syncthreads();                   // prior chunk's smem readers done
                if (tid < RPC) smem[tid] = 0.f;
                __syncthreads();
#pragma unroll
                for (int r = 0; r < RPC; ++r) {
                    float f[8];
                    up8(alo[r], f);
                    float sp = f[0] * vA[0] + f[1] * vA[1] + f[2] * vA[2] + f[3] * vA[3]
                             + f[4] * vA[4] + f[5] * vA[5] + f[6] * vA[6] + f[7] * vA[7];
                    up8(ahi[r], f);
                    sp += f[0] * vB[0] + f[1] * vB[1] + f[2] * vB[2] + f[3] * vB[3]
                        + f[4] * vB[4] + f[5] * vB[5] + f[6] * vB[6] + f[7] * vB[7];
#pragma unroll
                    for (int off = 32; off > 0; off >>= 1) sp += __shfl_xor(sp, off);
                    if (lane == 0) atomicAdd(&smem[r], sp);
                }
                __syncthreads();
                if (tid == 0) {                    // alpha partial (atomic hoisted)
#pragma unroll
                    for (int r = 0; r < RPC; ++r) aa_tot += smem[r] * smem[r];
                }
#pragma unroll
                for (int r = 0; r < RPC; ++r) {    // w += s_r * A_r (per-thread)
                    float s = smem[r];
                    float f[8];
                    up8(alo[r], f);
                    wacc[0] += s * f[0]; wacc[1] += s * f[1]; wacc[2] += s * f[2]; wacc[3] += s * f[3];
                    wacc[4] += s * f[4]; wacc[5] += s * f[5]; wacc[6] += s * f[6]; wacc[7] += s * f[7];
                    up8(ahi[r], f);
                    wacc[8] += s * f[0]; wacc[9] += s * f[1]; wacc[10] += s * f[2]; wacc[11] += s * f[3];
                    wacc[12] += s * f[4]; wacc[13] += s * f[5]; wacc[14] += s * f[6]; wacc[15] += s * f[7];
                }
            }
            if (tid == 0) atomicAdd(&slots[j], aa_tot);
            float* pb = partials + (size_t)bid * NCOLS;
            ic_st4_f32(pb + cA,     make_float4(wacc[0], wacc[1], wacc[2], wacc[3]));
            ic_st4_f32(pb + cA + 4, make_float4(wacc[4], wacc[5], wacc[6], wacc[7]));
            ic_st4_f32(pb + cB,     make_float4(wacc[8], wacc[9], wacc[10], wacc[11]));
            ic_st4_f32(pb + cB + 4, make_float4(wacc[12], wacc[13], wacc[14], wacc[15]));
        }
        gbar(arrive, release, errw, ++gen, bid);

        if (j < T_STEPS) {
            // ------------- fused reduce: 512 partials -> w, recurrence, beta --
            // Block b owns cols [8b, 8b+8). Thread: q=tid&1 (col-quad),
            // p0=tid>>1; sums partial rows {p0, p0+128, p0+256, p0+384}.
            {
                int q = tid & 1, p0 = tid >> 1;
                const float* pb0 = partials + (size_t)p0 * NCOLS + bid * 8 + q * 4;
                float4 v0, v1, v2, v3;
                ic_ld4_f32x4(pb0, pb0 + (size_t)128 * NCOLS,
                             pb0 + (size_t)256 * NCOLS, pb0 + (size_t)384 * NCOLS,
                             v0, v1, v2, v3);
                float4 s;
                s.x = v0.x + v1.x + v2.x + v3.x;
                s.y = v0.y + v1.y + v2.y + v3.y;
                s.z = v0.z + v1.z + v2.z + v3.z;
                s.w = v0.w + v1.w + v2.w + v3.w;
#pragma unroll
                for (int off = 2; off <= 32; off <<= 1) {   // reduce over p0 in wave
                    s.x += __shfl_xor(s.x, off);
                    s.y += __shfl_xor(s.y, off);
                    s.z += __shfl_xor(s.z, off);
                    s.w += __shfl_xor(s.w, off);
                }
                int lane = tid & 63, wv = tid >> 6;
                if (lane < 2) *(float4*)&smem[wv * 8 + lane * 4] = s;
                __syncthreads();
                if (tid < 8) {
                    int col = bid * 8 + tid;
                    float wsum = smem[tid] + smem[8 + tid] + smem[16 + tid] + smem[24 + tid];
                    float a = ic_ld_f32(&slots[j]);
                    float n2j = fmaxf(ic_ld_f32(&slots[64 + j]), 1e-30f);
                    float n2m = fmaxf(ic_ld_f32(&slots[64 + j - 1]), 1e-30f);
                    float invj = rsqrtf(n2j);
                    float cb = sqrtf(n2j / n2m);               // beta_{j-1}/||r_{j-1}||
                    float rn = wsum - a * invj * ic_ld_f32(&rc[col]) - cb * ic_ld_f32(&rp[col]);
                    ic_st_f32(&wt[col], rn);
                    float p = rn * rn;
                    p += __shfl_xor(p, 1);
                    p += __shfl_xor(p, 2);
                    p += __shfl_xor(p, 4);
                    if (tid == 0) atomicAdd(&slots[64 + j + 1], p);
                }
            }
            gbar(arrive, release, errw, ++gen, bid);
        }
    }

    // ---------------- solve: largest eig of tridiag via Sturm (block 0) -------
    if (bid == 0) {
        const int t = T_STEPS;
        float* d_s = smem;
        float* e2_s = smem + 64;
        if (tid < 64) {
            d_s[tid] = (tid < t) ? ic_ld_f32(&slots[1 + tid]) : 0.f;
            e2_s[tid] = (tid < t - 1) ? ic_ld_f32(&slots[64 + tid + 2]) : 0.f;
        }
        __syncthreads();
        if (tid < 64) {
            int lane = tid;
            float e_here = sqrtf(e2_s[lane]);
            float e_prev = (lane > 0) ? sqrtf(e2_s[lane - 1]) : 0.f;
            float d = d_s[lane];
            float gersh = (lane < t) ? d + e_here + e_prev : 0.f;
            float dmax = (lane < t) ? d : 0.f;
#pragma unroll
            for (int off = 32; off > 0; off >>= 1) {
                gersh = fmaxf(gersh, __shfl_xor(gersh, off));
                dmax = fmaxf(dmax, __shfl_xor(dmax, off));
            }
            float lo = dmax, hi = gersh + 1e-3f;
            for (int round = 0; round < 3; ++round) {
                float stepw = (hi - lo) * (1.f / 64.f);
                float x = lo + stepw * (lane + 1);
                double qv = 1.0;
                int cnt = 0;
                for (int i = 0; i < t; ++i) {
                    double qi = (double)d_s[i] - (double)x - ((i > 0) ? (double)e2_s[i - 1] / qv : 0.0);
                    if (fabs(qi) < 1e-300) qi = -1e-300;
                    cnt += (qi < 0.0);
                    qv = qi;
                }
                unsigned long long m = __ballot(cnt < t);
                if (m) {
                    int h = 63 - __clzll(m);
                    lo = lo + stepw * (h + 1);
                    hi = lo + stepw;
                } else {
                    hi = lo + stepw;
                }
            }
            if (tid == 0) {
                unsigned e = ic_ld_u32(errw);
                out[0] = e ? (-1.0e7f - (float)e) : 0.5f * (lo + hi);
            }
        }
    }
}

extern "C" void kernel_launch(void* const* d_in, const int* in_sizes, int n_in,
                              void* d_out, int out_size, void* d_ws, size_t ws_size,
                              hipStream_t stream) {
    const float* A = (const float*)d_in[0];
    float* out = (float*)d_out;
    float* ws = (float*)d_ws;
    __half* Ah = (__half*)((char*)d_ws + (size_t)16 * 1024 * 1024);

    // Zero barrier state: arrive counters + release gen + err (1024 B).
    hipMemsetAsync((char*)d_ws + (size_t)12416 * 4, 0, 1024, stream);

    lanczos_fused<<<NBLK, 256, 0, stream>>>(A, Ah, ws, out);
}

// Round 8
// 911.931 us; speedup vs baseline: 1.6264x; 1.1411x over previous
//
#include <hip/hip_runtime.h>
#include <hip/hip_fp16.h>
#include <math.h>

// BatchSpectralLoss: out = lambda_max(A^T A), A = 8192x4096 fp32 (k==1).
// SINGLE fused kernel, fence-free grid barrier, and REGISTER-RESIDENT A:
// R7 post-mortem: FETCH_SIZE 1.05GB = 16 x 64MB -> Ah was re-fetched from
// IC/HBM EVERY step (per-XCD working set 8MB > 4MiB L2 -> thrash) at ~1.7TB/s
// effective => ~600us of the 907us. Fix: each thread keeps its A-slice
// (16 rows x 16 cols fp16 = 512B = 128 VGPRs) in REGISTERS across all 16
// Lanczos steps. Ah never exists in memory; convert reads A (128MB, once)
// straight into regs. Per-step traffic drops 64MB -> ~8MB (partials+v).
// __launch_bounds__(256,2) caps VGPR at 256 -> exactly 2 blocks/CU -> 512
// blocks co-resident (bounded-spin + sticky err sentinel still guards).
// Barrier design unchanged from R7 (fence-free, write-through sc0 sc1 for all
// cross-block writes, bypass sc0 sc1 loads for all cross-block reads).
//
// ws float layout: vb0/vb1/vb2 at 0/4096/8192, slots at 12288
//   (alpha[j]=slots[j], norm2[j]=slots[64+j]), barrier at 12416
//   (8 arrive counters 64B-spaced, release gen at uint +192, err at +200;
//   1024B memset each launch), partials at 262144 (512x4096, ends 9 MiB).

#define NROWS 8192
#define NCOLS 4096
#define T_STEPS 16
#define NBLK 512
#define RPB 16           // rows per block (8192 / 512)
#define SPIN_LIMIT 200000L

typedef float f32x4_t __attribute__((ext_vector_type(4)));

// ---- coherence-point (Infinity Cache) accessors: bypass L1+L2, no cache ops
__device__ __forceinline__ unsigned ic_ld_u32(const unsigned* p) {
    unsigned v;
    asm volatile("global_load_dword %0, %1, off sc0 sc1\n\ts_waitcnt vmcnt(0)"
                 : "=v"(v) : "v"(p) : "memory");
    return v;
}
__device__ __forceinline__ float ic_ld_f32(const float* p) {
    float v;
    asm volatile("global_load_dword %0, %1, off sc0 sc1\n\ts_waitcnt vmcnt(0)"
                 : "=v"(v) : "v"(p) : "memory");
    return v;
}
__device__ __forceinline__ void ic_st_u32(unsigned* p, unsigned v) {
    asm volatile("global_store_dword %0, %1, off sc0 sc1"
                 :: "v"(p), "v"(v) : "memory");
}
__device__ __forceinline__ void ic_st_f32(float* p, float v) {
    asm volatile("global_store_dword %0, %1, off sc0 sc1"
                 :: "v"(p), "v"(v) : "memory");
}
__device__ __forceinline__ void ic_st4_f32(float* p, float4 v) {
    f32x4_t x; x.x = v.x; x.y = v.y; x.z = v.z; x.w = v.w;
    asm volatile("global_store_dwordx4 %0, %1, off sc0 sc1"
                 :: "v"(p), "v"(x) : "memory");
}
__device__ __forceinline__ unsigned ic_sum4_u32(const unsigned* p0, const unsigned* p1,
                                                const unsigned* p2, const unsigned* p3) {
    unsigned a, b, c, d;
    asm volatile(
        "global_load_dword %0, %4, off sc0 sc1\n\t"
        "global_load_dword %1, %5, off sc0 sc1\n\t"
        "global_load_dword %2, %6, off sc0 sc1\n\t"
        "global_load_dword %3, %7, off sc0 sc1\n\t"
        "s_waitcnt vmcnt(0)"
        : "=&v"(a), "=&v"(b), "=&v"(c), "=&v"(d)
        : "v"(p0), "v"(p1), "v"(p2), "v"(p3) : "memory");
    return a + b + c + d;
}
__device__ __forceinline__ void ic_ld4_f32x4(const float* p0, const float* p1,
                                             const float* p2, const float* p3,
                                             float4& ao, float4& bo, float4& co, float4& do_) {
    f32x4_t a, b, c, d;
    asm volatile(
        "global_load_dwordx4 %0, %4, off sc0 sc1\n\t"
        "global_load_dwordx4 %1, %5, off sc0 sc1\n\t"
        "global_load_dwordx4 %2, %6, off sc0 sc1\n\t"
        "global_load_dwordx4 %3, %7, off sc0 sc1\n\t"
        "s_waitcnt vmcnt(0)"
        : "=&v"(a), "=&v"(b), "=&v"(c), "=&v"(d)
        : "v"(p0), "v"(p1), "v"(p2), "v"(p3) : "memory");
    ao = make_float4(a.x, a.y, a.z, a.w);
    bo = make_float4(b.x, b.y, b.z, b.w);
    co = make_float4(c.x, c.y, c.z, c.w);
    do_ = make_float4(d.x, d.y, d.z, d.w);
}

__device__ __forceinline__ void up8(const float4& p, float* f) {
    const __half2* h = (const __half2*)&p;
    float2 t0 = __half22float2(h[0]);
    float2 t1 = __half22float2(h[1]);
    float2 t2 = __half22float2(h[2]);
    float2 t3 = __half22float2(h[3]);
    f[0] = t0.x; f[1] = t0.y; f[2] = t1.x; f[3] = t1.y;
    f[4] = t2.x; f[5] = t2.y; f[6] = t3.x; f[7] = t3.y;
}
__device__ __forceinline__ float4 pack8(const float4& a, const float4& b) {
    union { float4 f4; __half2 h2[4]; } u;
    u.h2[0] = __halves2half2(__float2half_rn(a.x), __float2half_rn(a.y));
    u.h2[1] = __halves2half2(__float2half_rn(a.z), __float2half_rn(a.w));
    u.h2[2] = __halves2half2(__float2half_rn(b.x), __float2half_rn(b.y));
    u.h2[3] = __halves2half2(__float2half_rn(b.z), __float2half_rn(b.w));
    return u.f4;
}

// Fence-free grid barrier (proven in R7). All cross-block data was written
// through to the IC; vmcnt(0) before the arrive RMW is the only ordering.
__device__ __forceinline__ void gbar(unsigned* arrive, unsigned* release,
                                     unsigned* errw, unsigned gen, int bid) {
    __syncthreads();
    if (threadIdx.x == 0) {
        asm volatile("s_waitcnt vmcnt(0)" ::: "memory");
        __hip_atomic_fetch_add(&arrive[(bid & 7) * 16], 1u,
                               __ATOMIC_RELAXED, __HIP_MEMORY_SCOPE_AGENT);
        if (ic_ld_u32(errw) == 0) {
            long iters = 0;
            if (bid == 0) {
                const unsigned target = gen * NBLK;
                for (;;) {
                    unsigned s = ic_sum4_u32(&arrive[0], &arrive[16], &arrive[32], &arrive[48])
                               + ic_sum4_u32(&arrive[64], &arrive[80], &arrive[96], &arrive[112]);
                    if (s >= target) break;
                    if (++iters > SPIN_LIMIT) { ic_st_u32(errw, gen); break; }
                    if ((iters & 255) == 0 && ic_ld_u32(errw)) break;
                    __builtin_amdgcn_s_sleep(2);
                }
                ic_st_u32(release, gen);
            } else {
                while (ic_ld_u32(release) < gen) {
                    if (++iters > SPIN_LIMIT) { ic_st_u32(errw, gen); break; }
                    if ((iters & 255) == 0 && ic_ld_u32(errw)) break;
                    __builtin_amdgcn_s_sleep(2);
                }
            }
        }
    }
    __syncthreads();
}

__global__ __launch_bounds__(256, 2) void lanczos_fused(const float* __restrict__ A,
                                                        float* __restrict__ ws,
                                                        float* __restrict__ out) {
    __shared__ __align__(16) float smem[192];
    float* slots = ws + 12288;
    unsigned* arrive = (unsigned*)(ws + 12416);
    unsigned* release = (unsigned*)(ws + 12416) + 192;
    unsigned* errw = (unsigned*)(ws + 12416) + 200;
    float* partials = ws + 262144;
    const int tid = threadIdx.x;
    const int bid = blockIdx.x;
    const int gtid = bid * 256 + tid;
    const int cA = tid * 8, cB = 2048 + tid * 8;
    unsigned gen = 0;

    // --- Phase A: load this thread's A-slice into registers (fp32->fp16) ----
    // Thread owns rows [bid*16, bid*16+16) x cols [cA,cA+8) u [cB,cB+8).
    float4 arA[RPB], arB[RPB];
    {
        const float* base = A + (size_t)bid * RPB * NCOLS;
#pragma unroll
        for (int r = 0; r < RPB; ++r) {
            const float* rowp = base + (size_t)r * NCOLS;
            float4 a0 = *(const float4*)(rowp + cA);
            float4 a1 = *(const float4*)(rowp + cA + 4);
            float4 b0 = *(const float4*)(rowp + cB);
            float4 b1 = *(const float4*)(rowp + cB + 4);
            arA[r] = pack8(a0, a1);
            arB[r] = pack8(b0, b1);
        }
        if (gtid < NCOLS) {
            unsigned h = (unsigned)gtid * 2654435761u;
            h ^= h >> 16; h *= 2246822519u; h ^= h >> 13;
            ic_st_f32(ws + 4096 + gtid, (h & 1u) ? 0.015625f : -0.015625f); // vb[1]
            ic_st_f32(ws + gtid, 0.f);                                      // vb[0]
            if (gtid < 128)
                ic_st_f32(slots + gtid, (gtid == 64 || gtid == 65) ? 1.f : 0.f);
        }
    }
    gbar(arrive, release, errw, ++gen, bid);

    for (int j = 1; j <= T_STEPS; ++j) {
        const float* rc = ws + 4096 * (j % 3);
        const float* rp = ws + 4096 * ((j + 2) % 3);
        float* wt = ws + 4096 * ((j + 1) % 3);

        // ---------------- bmv phase: partials = per-block A^T(Av), alpha ----
        {
            int lane = tid & 63;
            float inv = rsqrtf(fmaxf(ic_ld_f32(&slots[64 + j]), 1e-30f));
            float vA[8], vB[8];
            {
                float4 x, y, z, w4;
                ic_ld4_f32x4(rc + cA, rc + cA + 4, rc + cB, rc + cB + 4, x, y, z, w4);
                vA[0] = x.x * inv; vA[1] = x.y * inv; vA[2] = x.z * inv; vA[3] = x.w * inv;
                vA[4] = y.x * inv; vA[5] = y.y * inv; vA[6] = y.z * inv; vA[7] = y.w * inv;
                vB[0] = z.x * inv; vB[1] = z.y * inv; vB[2] = z.z * inv; vB[3] = z.w * inv;
                vB[4] = w4.x * inv; vB[5] = w4.y * inv; vB[6] = w4.z * inv; vB[7] = w4.w * inv;
            }
            __syncthreads();                  // prior phase's smem readers done
            if (tid < RPB) smem[tid] = 0.f;
            __syncthreads();
#pragma unroll
            for (int r = 0; r < RPB; ++r) {   // row dots (A from registers)
                float f[8];
                up8(arA[r], f);
                float sp = f[0] * vA[0] + f[1] * vA[1] + f[2] * vA[2] + f[3] * vA[3]
                         + f[4] * vA[4] + f[5] * vA[5] + f[6] * vA[6] + f[7] * vA[7];
                up8(arB[r], f);
                sp += f[0] * vB[0] + f[1] * vB[1] + f[2] * vB[2] + f[3] * vB[3]
                    + f[4] * vB[4] + f[5] * vB[5] + f[6] * vB[6] + f[7] * vB[7];
#pragma unroll
                for (int off = 32; off > 0; off >>= 1) sp += __shfl_xor(sp, off);
                if (lane == 0) atomicAdd(&smem[r], sp);
            }
            __syncthreads();
            if (tid == 0) {                   // alpha += sum_r s_r^2 (1 atomic)
                float aa = 0.f;
#pragma unroll
                for (int r = 0; r < RPB; ++r) aa += smem[r] * smem[r];
                atomicAdd(&slots[j], aa);
            }
            float wacc[16];
#pragma unroll
            for (int i = 0; i < 16; ++i) wacc[i] = 0.f;
#pragma unroll
            for (int r = 0; r < RPB; ++r) {   // w += s_r * A_r (per-thread)
                float s = smem[r];
                float f[8];
                up8(arA[r], f);
                wacc[0] += s * f[0]; wacc[1] += s * f[1]; wacc[2] += s * f[2]; wacc[3] += s * f[3];
                wacc[4] += s * f[4]; wacc[5] += s * f[5]; wacc[6] += s * f[6]; wacc[7] += s * f[7];
                up8(arB[r], f);
                wacc[8] += s * f[0]; wacc[9] += s * f[1]; wacc[10] += s * f[2]; wacc[11] += s * f[3];
                wacc[12] += s * f[4]; wacc[13] += s * f[5]; wacc[14] += s * f[6]; wacc[15] += s * f[7];
            }
            float* pb = partials + (size_t)bid * NCOLS;
            ic_st4_f32(pb + cA,     make_float4(wacc[0], wacc[1], wacc[2], wacc[3]));
            ic_st4_f32(pb + cA + 4, make_float4(wacc[4], wacc[5], wacc[6], wacc[7]));
            ic_st4_f32(pb + cB,     make_float4(wacc[8], wacc[9], wacc[10], wacc[11]));
            ic_st4_f32(pb + cB + 4, make_float4(wacc[12], wacc[13], wacc[14], wacc[15]));
        }
        gbar(arrive, release, errw, ++gen, bid);

        if (j < T_STEPS) {
            // ------------- fused reduce: 512 partials -> w, recurrence, beta --
            // Block b owns cols [8b, 8b+8). Thread: q=tid&1 (col-quad),
            // p0=tid>>1; sums partial rows {p0, p0+128, p0+256, p0+384}.
            {
                int q = tid & 1, p0 = tid >> 1;
                const float* pb0 = partials + (size_t)p0 * NCOLS + bid * 8 + q * 4;
                float4 v0, v1, v2, v3;
                ic_ld4_f32x4(pb0, pb0 + (size_t)128 * NCOLS,
                             pb0 + (size_t)256 * NCOLS, pb0 + (size_t)384 * NCOLS,
                             v0, v1, v2, v3);
                float4 s;
                s.x = v0.x + v1.x + v2.x + v3.x;
                s.y = v0.y + v1.y + v2.y + v3.y;
                s.z = v0.z + v1.z + v2.z + v3.z;
                s.w = v0.w + v1.w + v2.w + v3.w;
#pragma unroll
                for (int off = 2; off <= 32; off <<= 1) {
                    s.x += __shfl_xor(s.x, off);
                    s.y += __shfl_xor(s.y, off);
                    s.z += __shfl_xor(s.z, off);
                    s.w += __shfl_xor(s.w, off);
                }
                int lane = tid & 63, wv = tid >> 6;
                __syncthreads();              // bmv smem readers done
                if (lane < 2) *(float4*)&smem[32 + wv * 8 + lane * 4] = s;
                __syncthreads();
                if (tid < 8) {
                    int col = bid * 8 + tid;
                    float wsum = smem[32 + tid] + smem[40 + tid] + smem[48 + tid] + smem[56 + tid];
                    float a = ic_ld_f32(&slots[j]);
                    float n2j = fmaxf(ic_ld_f32(&slots[64 + j]), 1e-30f);
                    float n2m = fmaxf(ic_ld_f32(&slots[64 + j - 1]), 1e-30f);
                    float invj = rsqrtf(n2j);
                    float cb = sqrtf(n2j / n2m);               // beta_{j-1}/||r_{j-1}||
                    float rn = wsum - a * invj * ic_ld_f32(&rc[col]) - cb * ic_ld_f32(&rp[col]);
                    ic_st_f32(&wt[col], rn);
                    float p = rn * rn;
                    p += __shfl_xor(p, 1);
                    p += __shfl_xor(p, 2);
                    p += __shfl_xor(p, 4);
                    if (tid == 0) atomicAdd(&slots[64 + j + 1], p);
                }
            }
            gbar(arrive, release, errw, ++gen, bid);
        }
    }

    // ---------------- solve: largest eig of tridiag via Sturm (block 0) -------
    if (bid == 0) {
        const int t = T_STEPS;
        float* d_s = smem;
        float* e2_s = smem + 64;
        if (tid < 64) {
            d_s[tid] = (tid < t) ? ic_ld_f32(&slots[1 + tid]) : 0.f;
            e2_s[tid] = (tid < t - 1) ? ic_ld_f32(&slots[64 + tid + 2]) : 0.f;
        }
        __syncthreads();
        if (tid < 64) {
            int lane = tid;
            float e_here = sqrtf(e2_s[lane]);
            float e_prev = (lane > 0) ? sqrtf(e2_s[lane - 1]) : 0.f;
            float d = d_s[lane];
            float gersh = (lane < t) ? d + e_here + e_prev : 0.f;
            float dmax = (lane < t) ? d : 0.f;
#pragma unroll
            for (int off = 32; off > 0; off >>= 1) {
                gersh = fmaxf(gersh, __shfl_xor(gersh, off));
                dmax = fmaxf(dmax, __shfl_xor(dmax, off));
            }
            float lo = dmax, hi = gersh + 1e-3f;
            for (int round = 0; round < 3; ++round) {
                float stepw = (hi - lo) * (1.f / 64.f);
                float x = lo + stepw * (lane + 1);
                double qv = 1.0;
                int cnt = 0;
                for (int i = 0; i < t; ++i) {
                    double qi = (double)d_s[i] - (double)x - ((i > 0) ? (double)e2_s[i - 1] / qv : 0.0);
                    if (fabs(qi) < 1e-300) qi = -1e-300;
                    cnt += (qi < 0.0);
                    qv = qi;
                }
                unsigned long long m = __ballot(cnt < t);
                if (m) {
                    int h = 63 - __clzll(m);
                    lo = lo + stepw * (h + 1);
                    hi = lo + stepw;
                } else {
                    hi = lo + stepw;
                }
            }
            if (tid == 0) {
                unsigned e = ic_ld_u32(errw);
                out[0] = e ? (-1.0e7f - (float)e) : 0.5f * (lo + hi);
            }
        }
    }
}

extern "C" void kernel_launch(void* const* d_in, const int* in_sizes, int n_in,
                              void* d_out, int out_size, void* d_ws, size_t ws_size,
                              hipStream_t stream) {
    const float* A = (const float*)d_in[0];
    float* out = (float*)d_out;
    float* ws = (float*)d_ws;

    // Zero barrier state: arrive counters + release gen + err (1024 B).
    hipMemsetAsync((char*)d_ws + (size_t)12416 * 4, 0, 1024, stream);

    lanczos_fused<<<NBLK, 256, 0, stream>>>(A, ws, out);
}